// Round 1
// baseline (63.749 us; speedup 1.0000x reference)
//
#include <hip/hip_runtime.h>

#define REF_EPS 0.001f

// R5: latency-overlap reorder.
// Previous structure serialized per wave: x-load -> ds_write -> barrier ->
// grid L2 loads -> coeff VALU -> gather. Grid loads could not be hoisted
// above the barrier (fence), so ~400-600 cyc of L2 latency + coeff math sat
// on the critical path after staging. New order: issue grid loads FIRST,
// then x loads, compute validity+coeffs+indices in registers while x is in
// flight, stage, ONE barrier, gather. Also dedups the own-n grid re-read
// (selected from validity-loop registers with compile-time unrolled if,
// not pa[n] runtime indexing -> would spill to scratch).
template<int N, int C, int H, int W>
__global__ __launch_bounds__(1024)
void fused_remap2_t(const float* __restrict__ x,
                    const float* __restrict__ grid,
                    float* __restrict__ out) {
    constexpr int HW = H * W;
    constexpr int CB = C / 2;          // row-pairs per n
    __shared__ float xs0[HW];
    __shared__ float xs1[HW];

    const int n = blockIdx.x / CB;     // constexpr -> shift
    const int tid = threadIdx.x;
    const size_t row0 = (size_t)blockIdx.x * 2;   // = n*C + 2*cb

    constexpr float hx = (float)(H - 1);
    constexpr float wy = (float)(W - 1);
    const float4* g4 = (const float4*)grid;   // 2 (gx,gy) pairs per float4
    const int k0 = tid << 2;                  // 4 consecutive k's per thread

    // ---- issue ALL grid loads first (L2-hot; coeff phase needs them) ----
    float4 pa[N], pb[N];
    #pragma unroll
    for (int m = 0; m < N; ++m) {
        const int base = (m * HW + k0) >> 1;
        pa[m] = g4[base];       // gx[k0],gy[k0],gx[k0+1],gy[k0+1]
        pb[m] = g4[base + 1];   // gx[k0+2],gy[k0+2],gx[k0+3],gy[k0+3]
    }

    // ---- then issue the two x-row loads (HBM, ~600-900 cyc) ----
    const float4* xv = (const float4*)(x + row0 * HW);
    float4 xr0 = xv[tid];
    float4 xr1 = xv[tid + (HW >> 2)];

    // ---- validity across ALL n (registers only; overlaps x latency) ----
    bool v[4] = {true, true, true, true};
    #pragma unroll
    for (int m = 0; m < N; ++m) {
        v[0] = v[0] && (pa[m].x >= -REF_EPS) && (pa[m].x <= hx + REF_EPS)
                    && (pa[m].y >= -REF_EPS) && (pa[m].y <= wy + REF_EPS);
        v[1] = v[1] && (pa[m].z >= -REF_EPS) && (pa[m].z <= hx + REF_EPS)
                    && (pa[m].w >= -REF_EPS) && (pa[m].w <= wy + REF_EPS);
        v[2] = v[2] && (pb[m].x >= -REF_EPS) && (pb[m].x <= hx + REF_EPS)
                    && (pb[m].y >= -REF_EPS) && (pb[m].y <= wy + REF_EPS);
        v[3] = v[3] && (pb[m].z >= -REF_EPS) && (pb[m].z <= hx + REF_EPS)
                    && (pb[m].w >= -REF_EPS) && (pb[m].w <= wy + REF_EPS);
    }

    // ---- own-n grid values: select from already-loaded regs (dedup) ----
    float4 oa = pa[0], ob = pb[0];
    #pragma unroll
    for (int m = 1; m < N; ++m) {
        if (n == m) { oa = pa[m]; ob = pb[m]; }   // uniform cond, static idx
    }
    float g0[4] = {oa.x, oa.z, ob.x, ob.z};
    float g1[4] = {oa.y, oa.w, ob.y, ob.w};

    // ---- coeffs + corner indices, still before the barrier ----
    int   c0[4];
    float w0[4], w1[4], w2[4], w3[4];
    #pragma unroll
    for (int j = 0; j < 4; ++j) {
        float gx = fminf(fmaxf(g0[j], REF_EPS), hx - REF_EPS);
        float gy = fminf(fmaxf(g1[j], REF_EPS), wy - REF_EPS);
        float ixf = floorf(gx);
        float iyf = floorf(gy);
        float fx = gx - ixf;
        float fy = gy - iyf;
        c0[j] = (int)ixf * W + (int)iyf;
        float omfx = 1.0f - fx;
        // coeffs = outer([1-fx, fx], [fx, fy]) flattened (faithful to source)
        w0[j] = omfx * fx;
        w1[j] = omfx * fy;
        w2[j] = fx * fx;
        w3[j] = fx * fy;
    }

    // ---- stage x rows to LDS (first point that needs the x data) ----
    ((float4*)xs0)[tid] = xr0;
    ((float4*)xs1)[tid] = xr1;
    __syncthreads();

    // ---- gather: 4 ds_read2_b32 pairs per j, two rows ----
    float4 r0, r1;
    float* r0p = &r0.x;
    float* r1p = &r1.x;
    #pragma unroll
    for (int j = 0; j < 4; ++j) {
        int c = c0[j];
        float a0 = xs0[c] * w0[j] + xs0[c + 1] * w1[j]
                 + xs0[c + W] * w2[j] + xs0[c + W + 1] * w3[j];
        float a1 = xs1[c] * w0[j] + xs1[c + 1] * w1[j]
                 + xs1[c + W] * w2[j] + xs1[c + W + 1] * w3[j];
        r0p[j] = v[j] ? a0 : 0.0f;   // select, not multiply: kills NaN garbage
        r1p[j] = v[j] ? a1 : 0.0f;
    }
    float4* ov = (float4*)(out + row0 * HW);
    ov[tid] = r0;
    ov[tid + (HW >> 2)] = r1;
}

// ---------------- generic fallback (runtime shapes) -------------------------
__global__ __launch_bounds__(1024)
void fused_remap_generic(const float* __restrict__ x,
                         const float* __restrict__ grid,
                         float* __restrict__ out,
                         int N, int C, int H, int W) {
    const int HW = H * W;
    extern __shared__ float xs[];
    const int row = blockIdx.x;
    const int n = row / C;
    const int tid = threadIdx.x;

    for (int i = tid; i < HW; i += 1024) xs[i] = x[(size_t)row * HW + i];
    __syncthreads();

    const float hx = (float)(H - 1);
    const float wy = (float)(W - 1);

    for (int k = tid; k < HW; k += 1024) {
        bool valid = true;
        for (int m = 0; m < N; ++m) {
            float a = grid[((size_t)m * HW + k) * 2 + 0];
            float b = grid[((size_t)m * HW + k) * 2 + 1];
            valid = valid && (a >= -REF_EPS) && (a <= hx + REF_EPS)
                          && (b >= -REF_EPS) && (b <= wy + REF_EPS);
        }
        float g0v = grid[((size_t)n * HW + k) * 2 + 0];
        float g1v = grid[((size_t)n * HW + k) * 2 + 1];
        float gx = fminf(fmaxf(g0v, REF_EPS), hx - REF_EPS);
        float gy = fminf(fmaxf(g1v, REF_EPS), wy - REF_EPS);
        float ixf = floorf(gx), iyf = floorf(gy);
        float fx = gx - ixf, fy = gy - iyf;
        int c0 = (int)ixf * W + (int)iyf;
        float omfx = 1.0f - fx;
        float r = xs[c0] * (omfx * fx) + xs[c0 + 1] * (omfx * fy)
                + xs[c0 + W] * (fx * fx) + xs[c0 + W + 1] * (fx * fy);
        out[(size_t)row * HW + k] = valid ? r : 0.0f;
    }
}

extern "C" void kernel_launch(void* const* d_in, const int* in_sizes, int n_in,
                              void* d_out, int out_size, void* d_ws, size_t ws_size,
                              hipStream_t stream) {
    const float* x    = (const float*)d_in[0];  // (N, C, HW) fp32
    const float* grid = (const float*)d_in[1];  // (N, H, W, 2) fp32
    float* out = (float*)d_out;                 // (N, C, HW) fp32

    const int H = 64, W = 64;
    const int HW = H * W;
    const int N = in_sizes[1] / (HW * 2);
    const int C = in_sizes[0] / (N * HW);

    if (N == 4 && C == 128) {
        hipLaunchKernelGGL((fused_remap2_t<4, 128, 64, 64>), dim3(N * C / 2),
                           dim3(1024), 0, stream, x, grid, out);
    } else {
        const size_t shmem = (size_t)HW * sizeof(float);
        hipLaunchKernelGGL(fused_remap_generic, dim3(N * C), dim3(1024), shmem,
                           stream, x, grid, out, N, C, H, W);
    }
}